// Round 1
// baseline (559.565 us; speedup 1.0000x reference)
//
#include <hip/hip_runtime.h>

// AggregationLoss: two-pass segment-sum + per-pixel loss reduction.
// Pass 1: per-batch per-label sums (ksum, rsum, psum[c]) + max(klab[last]).
// Pass 2: per-pixel Gk gather, hinge-log loss, global scalar reduction.

constexpr int NSEG = 33;
constexpr int NCH  = 4;
constexpr int WS_PER_B = NSEG * (NCH + 2);  // 198 floats per batch
constexpr float SIGMA_AGG = 0.5f;

// ws per-batch layout: [0,33)=ksum, [33,66)=rsum, [66,198)=psum[c*33+s]

__global__ __launch_bounds__(256) void seg_sums_kernel(
    const float* __restrict__ pred, const float* __restrict__ kmask,
    const int* __restrict__ rlab, const int* __restrict__ klab,
    float* __restrict__ ws, int* __restrict__ numk_out,
    int N, int lastB)
{
    const int b = blockIdx.y;
    __shared__ float s_acc[WS_PER_B];
    __shared__ int s_maxk;
    for (int j = threadIdx.x; j < WS_PER_B; j += blockDim.x) s_acc[j] = 0.0f;
    if (threadIdx.x == 0) s_maxk = 0;
    __syncthreads();

    const size_t bN = (size_t)b * N;
    const int Nv = N >> 2;
    const float4* __restrict__ predv = (const float4*)(pred + (size_t)b * NCH * N);
    const float4* __restrict__ kmv   = (const float4*)(kmask + bN);
    const int4*   __restrict__ rlv   = (const int4*)(rlab + bN);
    const int4*   __restrict__ klv   = (const int4*)(klab + bN);

    int mk = 0;
    for (int i = blockIdx.x * blockDim.x + threadIdx.x; i < Nv;
         i += gridDim.x * blockDim.x) {
        float4 km = kmv[i];
        int4   kl = klv[i];
        int4   rl = rlv[i];
        float4 p0 = predv[0 * Nv + i];
        float4 p1 = predv[1 * Nv + i];
        float4 p2 = predv[2 * Nv + i];
        float4 p3 = predv[3 * Nv + i];

        #define PIX(sfx) do {                                        \
            int kl_ = kl.sfx, rl_ = rl.sfx; float km_ = km.sfx;      \
            atomicAdd(&s_acc[kl_], km_);                             \
            atomicAdd(&s_acc[NSEG + rl_], km_);                      \
            atomicAdd(&s_acc[2 * NSEG + 0 * NSEG + kl_], p0.sfx);    \
            atomicAdd(&s_acc[2 * NSEG + 1 * NSEG + kl_], p1.sfx);    \
            atomicAdd(&s_acc[2 * NSEG + 2 * NSEG + kl_], p2.sfx);    \
            atomicAdd(&s_acc[2 * NSEG + 3 * NSEG + kl_], p3.sfx);    \
            mk = max(mk, kl_);                                       \
        } while (0)
        PIX(x); PIX(y); PIX(z); PIX(w);
        #undef PIX
    }
    __syncthreads();

    float* wsb = ws + b * WS_PER_B;
    for (int j = threadIdx.x; j < WS_PER_B; j += blockDim.x)
        atomicAdd(&wsb[j], s_acc[j]);

    if (b == lastB) {
        atomicMax(&s_maxk, mk);
        __syncthreads();
        if (threadIdx.x == 0) atomicMax(numk_out, s_maxk);
    }
}

__global__ __launch_bounds__(256) void loss_kernel(
    const float* __restrict__ pred, const float* __restrict__ rmask,
    const int* __restrict__ rlab, const int* __restrict__ klab,
    const float* __restrict__ ws, const int* __restrict__ numk,
    float* __restrict__ out, int N)
{
    const int b = blockIdx.y;
    __shared__ float s_gk[NCH * NSEG];   // psum[c][s] / (ksum[s]+1); 0 for s==0
    __shared__ float s_rinv[NSEG];       // 1/(rsum[s]+1); slot 0 = 1.0 (rcard=0 case)
    __shared__ float s_part[4];
    const float* wsb = ws + b * WS_PER_B;
    for (int j = threadIdx.x; j < NSEG; j += blockDim.x) {
        float rs = wsb[NSEG + j];
        s_rinv[j] = (j > 0) ? 1.0f / (rs + 1.0f) : 1.0f;
    }
    for (int j = threadIdx.x; j < NCH * NSEG; j += blockDim.x) {
        int s = j % NSEG;
        float ks = wsb[s];
        s_gk[j] = (s > 0) ? wsb[2 * NSEG + j] / (ks + 1.0f) : 0.0f;
    }
    __syncthreads();

    const float inv_nk = 1.0f / (float)(*numk);
    const size_t bN = (size_t)b * N;
    const int Nv = N >> 2;
    const float4* __restrict__ predv = (const float4*)(pred + (size_t)b * NCH * N);
    const float4* __restrict__ rmv   = (const float4*)(rmask + bN);
    const int4*   __restrict__ rlv   = (const int4*)(rlab + bN);
    const int4*   __restrict__ klv   = (const int4*)(klab + bN);

    float acc = 0.0f;
    for (int i = blockIdx.x * blockDim.x + threadIdx.x; i < Nv;
         i += gridDim.x * blockDim.x) {
        float4 rm = rmv[i];
        int4   kl = klv[i];
        int4   rl = rlv[i];
        float4 p0 = predv[0 * Nv + i];
        float4 p1 = predv[1 * Nv + i];
        float4 p2 = predv[2 * Nv + i];
        float4 p3 = predv[3 * Nv + i];

        #define PIX(sfx) do {                                        \
            int kl_ = kl.sfx, rl_ = rl.sfx; float rm_ = rm.sfx;      \
            float d0 = fmaf(p0.sfx, rm_, -s_gk[0 * NSEG + kl_]);     \
            float d1 = fmaf(p1.sfx, rm_, -s_gk[1 * NSEG + kl_]);     \
            float d2 = fmaf(p2.sfx, rm_, -s_gk[2 * NSEG + kl_]);     \
            float d3 = fmaf(p3.sfx, rm_, -s_gk[3 * NSEG + kl_]);     \
            float ss = d0*d0 + d1*d1 + d2*d2 + d3*d3;                \
            float nrm = sqrtf(ss);                                   \
            float dd = fmaxf(nrm - SIGMA_AGG, 0.0f);                 \
            acc += __logf(fmaf(dd, dd, 1.0f)) * s_rinv[rl_];         \
        } while (0)
        PIX(x); PIX(y); PIX(z); PIX(w);
        #undef PIX
    }

    // wave (64-lane) reduce, then cross-wave via LDS
    for (int off = 32; off > 0; off >>= 1)
        acc += __shfl_down(acc, off);
    const int lane = threadIdx.x & 63;
    const int wid  = threadIdx.x >> 6;
    if (lane == 0) s_part[wid] = acc;
    __syncthreads();
    if (threadIdx.x == 0) {
        float t = s_part[0] + s_part[1] + s_part[2] + s_part[3];
        atomicAdd(out, t * inv_nk);
    }
}

extern "C" void kernel_launch(void* const* d_in, const int* in_sizes, int n_in,
                              void* d_out, int out_size, void* d_ws, size_t ws_size,
                              hipStream_t stream)
{
    const float* pred  = (const float*)d_in[0];
    const float* rmask = (const float*)d_in[1];
    const float* kmask = (const float*)d_in[2];
    const int*   rlab  = (const int*)d_in[3];
    const int*   klab  = (const int*)d_in[4];
    float* out = (float*)d_out;

    const int B = 16;
    const int N = in_sizes[1] / B;   // H*W per batch

    float* wsf = (float*)d_ws;
    int* numk = (int*)((char*)d_ws + (size_t)B * WS_PER_B * sizeof(float));

    // ws and out are poisoned 0xAA before every launch — zero what we use.
    hipMemsetAsync(d_ws, 0, (size_t)B * WS_PER_B * sizeof(float) + sizeof(int), stream);
    hipMemsetAsync(d_out, 0, sizeof(float), stream);

    dim3 block(256);
    dim3 grid(128, B);   // 2048 blocks = 8/CU
    seg_sums_kernel<<<grid, block, 0, stream>>>(pred, kmask, rlab, klab, wsf, numk, N, B - 1);
    loss_kernel<<<grid, block, 0, stream>>>(pred, rmask, rlab, klab, wsf, numk, out, N);
}

// Round 2
// 327.452 us; speedup vs baseline: 1.7088x; 1.7088x over previous
//
#include <hip/hip_runtime.h>

// AggregationLoss: two-pass segment-sum + per-pixel loss reduction.
// Pass 1: per-batch per-label sums (ksum, rsum, psum[c]) in INT fixed-point
//         (ds_add_u32 / global_atomic_add are native; float atomicAdd is a
//         CAS loop on gfx950 -> 322us stall storm in round 1).
// Pass 2: per-pixel Gk gather, hinge-log loss, per-block partial (plain store).
// Pass 3: 1-block finalize reduces partials, divides by num_kernel.

constexpr int NSEG = 33;
constexpr int NCH  = 4;
constexpr int WS_PER_B = NSEG * (NCH + 2);  // 198 ints per batch
constexpr float SIGMA_AGG = 0.5f;
constexpr float QSCALE = 32768.0f;          // 2^15 fixed point
constexpr float QINV   = 1.0f / 32768.0f;

// ws layout (ints): [0, B*198) pass-1 tables, [B*198] numk,
// then (float) partials at int offset 3200.
constexpr int NUMK_OFF = 16 * WS_PER_B;     // 3168
constexpr int PART_OFF = 3200;

__global__ __launch_bounds__(256) void seg_sums_kernel(
    const float* __restrict__ pred, const float* __restrict__ kmask,
    const int* __restrict__ rlab, const int* __restrict__ klab,
    int* __restrict__ ws, int* __restrict__ numk_out,
    int N, int lastB)
{
    const int b = blockIdx.y;
    __shared__ int s_acc[WS_PER_B];
    __shared__ int s_maxk;
    for (int j = threadIdx.x; j < WS_PER_B; j += blockDim.x) s_acc[j] = 0;
    if (threadIdx.x == 0) s_maxk = 0;
    __syncthreads();

    const size_t bN = (size_t)b * N;
    const int Nv = N >> 2;
    const float4* __restrict__ predv = (const float4*)(pred + (size_t)b * NCH * N);
    const float4* __restrict__ kmv   = (const float4*)(kmask + bN);
    const int4*   __restrict__ rlv   = (const int4*)(rlab + bN);
    const int4*   __restrict__ klv   = (const int4*)(klab + bN);

    int mk = 0;
    for (int i = blockIdx.x * blockDim.x + threadIdx.x; i < Nv;
         i += gridDim.x * blockDim.x) {
        float4 km = kmv[i];
        int4   kl = klv[i];
        int4   rl = rlv[i];
        float4 p0 = predv[0 * Nv + i];
        float4 p1 = predv[1 * Nv + i];
        float4 p2 = predv[2 * Nv + i];
        float4 p3 = predv[3 * Nv + i];

        #define PIX(sfx) do {                                                 \
            int kl_ = kl.sfx, rl_ = rl.sfx;                                   \
            int kq = __float2int_rn(km.sfx * QSCALE);                         \
            atomicAdd(&s_acc[kl_], kq);                                       \
            atomicAdd(&s_acc[NSEG + rl_], kq);                                \
            atomicAdd(&s_acc[2 * NSEG + 0 * NSEG + kl_],                      \
                      __float2int_rn(p0.sfx * QSCALE));                       \
            atomicAdd(&s_acc[2 * NSEG + 1 * NSEG + kl_],                      \
                      __float2int_rn(p1.sfx * QSCALE));                       \
            atomicAdd(&s_acc[2 * NSEG + 2 * NSEG + kl_],                      \
                      __float2int_rn(p2.sfx * QSCALE));                       \
            atomicAdd(&s_acc[2 * NSEG + 3 * NSEG + kl_],                      \
                      __float2int_rn(p3.sfx * QSCALE));                       \
            mk = max(mk, kl_);                                                \
        } while (0)
        PIX(x); PIX(y); PIX(z); PIX(w);
        #undef PIX
    }
    __syncthreads();

    int* wsb = ws + b * WS_PER_B;
    for (int j = threadIdx.x; j < WS_PER_B; j += blockDim.x)
        atomicAdd(&wsb[j], s_acc[j]);           // int: native global atomic

    if (b == lastB) {
        atomicMax(&s_maxk, mk);
        __syncthreads();
        if (threadIdx.x == 0) atomicMax(numk_out, s_maxk);
    }
}

__global__ __launch_bounds__(256) void loss_kernel(
    const float* __restrict__ pred, const float* __restrict__ rmask,
    const int* __restrict__ rlab, const int* __restrict__ klab,
    const int* __restrict__ ws, float* __restrict__ partials, int N)
{
    const int b = blockIdx.y;
    __shared__ float s_gk[NCH * NSEG];   // psum[c][s] / (ksum[s]+1); 0 for s==0
    __shared__ float s_rinv[NSEG];       // 1/(rsum[s]+1); slot 0 = 1.0 (rcard=0)
    __shared__ float s_part[4];
    const int* wsb = ws + b * WS_PER_B;
    for (int j = threadIdx.x; j < NSEG; j += blockDim.x) {
        float rs = (float)wsb[NSEG + j] * QINV;
        s_rinv[j] = (j > 0) ? 1.0f / (rs + 1.0f) : 1.0f;
    }
    for (int j = threadIdx.x; j < NCH * NSEG; j += blockDim.x) {
        int s = j % NSEG;
        float ks = (float)wsb[s] * QINV;
        float ps = (float)wsb[2 * NSEG + j] * QINV;
        s_gk[j] = (s > 0) ? ps / (ks + 1.0f) : 0.0f;
    }
    __syncthreads();

    const size_t bN = (size_t)b * N;
    const int Nv = N >> 2;
    const float4* __restrict__ predv = (const float4*)(pred + (size_t)b * NCH * N);
    const float4* __restrict__ rmv   = (const float4*)(rmask + bN);
    const int4*   __restrict__ rlv   = (const int4*)(rlab + bN);
    const int4*   __restrict__ klv   = (const int4*)(klab + bN);

    float acc = 0.0f;
    for (int i = blockIdx.x * blockDim.x + threadIdx.x; i < Nv;
         i += gridDim.x * blockDim.x) {
        float4 rm = rmv[i];
        int4   kl = klv[i];
        int4   rl = rlv[i];
        float4 p0 = predv[0 * Nv + i];
        float4 p1 = predv[1 * Nv + i];
        float4 p2 = predv[2 * Nv + i];
        float4 p3 = predv[3 * Nv + i];

        #define PIX(sfx) do {                                        \
            int kl_ = kl.sfx, rl_ = rl.sfx; float rm_ = rm.sfx;      \
            float d0 = fmaf(p0.sfx, rm_, -s_gk[0 * NSEG + kl_]);     \
            float d1 = fmaf(p1.sfx, rm_, -s_gk[1 * NSEG + kl_]);     \
            float d2 = fmaf(p2.sfx, rm_, -s_gk[2 * NSEG + kl_]);     \
            float d3 = fmaf(p3.sfx, rm_, -s_gk[3 * NSEG + kl_]);     \
            float ss = d0*d0 + d1*d1 + d2*d2 + d3*d3;                \
            float nrm = sqrtf(ss);                                   \
            float dd = fmaxf(nrm - SIGMA_AGG, 0.0f);                 \
            acc += __logf(fmaf(dd, dd, 1.0f)) * s_rinv[rl_];         \
        } while (0)
        PIX(x); PIX(y); PIX(z); PIX(w);
        #undef PIX
    }

    // wave (64-lane) reduce, then cross-wave via LDS; plain store (no atomic)
    for (int off = 32; off > 0; off >>= 1)
        acc += __shfl_down(acc, off);
    const int lane = threadIdx.x & 63;
    const int wid  = threadIdx.x >> 6;
    if (lane == 0) s_part[wid] = acc;
    __syncthreads();
    if (threadIdx.x == 0)
        partials[blockIdx.y * gridDim.x + blockIdx.x] =
            s_part[0] + s_part[1] + s_part[2] + s_part[3];
}

__global__ __launch_bounds__(256) void finalize_kernel(
    const float* __restrict__ partials, const int* __restrict__ numk,
    float* __restrict__ out, int nPart)
{
    __shared__ float s_part[4];
    float a = 0.0f;
    for (int i = threadIdx.x; i < nPart; i += blockDim.x) a += partials[i];
    for (int off = 32; off > 0; off >>= 1)
        a += __shfl_down(a, off);
    if ((threadIdx.x & 63) == 0) s_part[threadIdx.x >> 6] = a;
    __syncthreads();
    if (threadIdx.x == 0)
        out[0] = (s_part[0] + s_part[1] + s_part[2] + s_part[3]) / (float)(*numk);
}

extern "C" void kernel_launch(void* const* d_in, const int* in_sizes, int n_in,
                              void* d_out, int out_size, void* d_ws, size_t ws_size,
                              hipStream_t stream)
{
    const float* pred  = (const float*)d_in[0];
    const float* rmask = (const float*)d_in[1];
    const float* kmask = (const float*)d_in[2];
    const int*   rlab  = (const int*)d_in[3];
    const int*   klab  = (const int*)d_in[4];
    float* out = (float*)d_out;

    const int B = 16;
    const int N = in_sizes[1] / B;   // H*W per batch

    int* wsi = (int*)d_ws;
    int* numk = wsi + NUMK_OFF;
    float* partials = (float*)(wsi + PART_OFF);

    // ws is poisoned 0xAA before every launch — zero the accumulator tables.
    hipMemsetAsync(d_ws, 0, (size_t)(NUMK_OFF + 1) * sizeof(int), stream);

    dim3 block(256);
    dim3 grid(256, B);   // 4096 blocks
    seg_sums_kernel<<<grid, block, 0, stream>>>(pred, kmask, rlab, klab, wsi, numk, N, B - 1);
    loss_kernel<<<grid, block, 0, stream>>>(pred, rmask, rlab, klab, wsi, partials, N);
    finalize_kernel<<<dim3(1), block, 0, stream>>>(partials, numk, out, 256 * B);
}